// Round 9
// baseline (946.948 us; speedup 1.0000x reference)
//
#include <hip/hip_runtime.h>
#include <hip/hip_bf16.h>
#include <math.h>

#define NTOK 8192
#define DDIM 1024
#define HDIM 4096
#define NEXP 8
#define KTOP 2
#define MAXROWS 18432   /* 16384 + 8*256 */
#define MAXTILES 72     /* 256-row tiles */

typedef __bf16 bf16x8 __attribute__((ext_vector_type(8)));
typedef float f32x4 __attribute__((ext_vector_type(4)));

#define GAS __attribute__((address_space(1)))
#define LAS __attribute__((address_space(3)))

__device__ __forceinline__ void async16(const void* g, void* l) {
  __builtin_amdgcn_global_load_lds((GAS void*)g, (LAS void*)l, 16, 0, 0);
}

// ---------------- workspace layout (bytes) ----------------
#define XB_OFF     ((size_t)0)
#define W1T_OFF    (XB_OFF + (size_t)NTOK*DDIM*2)
#define ROWOUT_OFF W1T_OFF              /* w1t dead after gemm1; rowout 37.7MB < 64MB */
#define W2T_OFF    (W1T_OFF + (size_t)NEXP*DDIM*HDIM*2)
#define HB_OFF     (W2T_OFF + (size_t)NEXP*HDIM*DDIM*2)
#define ROWTOK_OFF (HB_OFF + (size_t)MAXROWS*HDIM*2)
#define ROWW_OFF   (ROWTOK_OFF + (size_t)MAXROWS*4)
#define TOKE_OFF   (ROWW_OFF + (size_t)MAXROWS*4)
#define TOKW_OFF   (TOKE_OFF + (size_t)NTOK*KTOP*4)
#define TOKROW_OFF (TOKW_OFF + (size_t)NTOK*KTOP*4)
#define TILEE_OFF  (TOKROW_OFF + (size_t)NTOK*KTOP*4)
#define CNT_OFF    (TILEE_OFF + (size_t)256*4)
#define POS_OFF    (CNT_OFF + 64)
#define IMP_OFF    (POS_OFF + 64)
#define META_OFF   (IMP_OFF + 64)

// ---------------- small utility kernels ----------------
__global__ void init_kernel(int* counts, float* importance) {
  if (threadIdx.x < NEXP) { counts[threadIdx.x] = 0; importance[threadIdx.x] = 0.f; }
}

__global__ void cast_x_kernel(const float* __restrict__ src, __hip_bfloat16* __restrict__ dst) {
  size_t i = ((size_t)blockIdx.x * blockDim.x + threadIdx.x) * 4;
  if (i < (size_t)NTOK * DDIM) {
    float4 v = *(const float4*)(src + i);
    dst[i + 0] = __float2bfloat16(v.x);
    dst[i + 1] = __float2bfloat16(v.y);
    dst[i + 2] = __float2bfloat16(v.z);
    dst[i + 3] = __float2bfloat16(v.w);
  }
}

// per-expert transpose+cast: src [E][R][C] fp32 -> dst [E][C][R] bf16
__global__ __launch_bounds__(256) void transpose_cast_kernel(
    const float* __restrict__ src, __hip_bfloat16* __restrict__ dst, int R, int C) {
  __shared__ float tile[64][65];
  const int e = blockIdx.z;
  const float* s = src + (size_t)e * R * C;
  __hip_bfloat16* d = dst + (size_t)e * R * C;
  const int c0 = blockIdx.x * 64, r0 = blockIdx.y * 64;
  const int tc = (threadIdx.x & 15) * 4;
  const int tr = threadIdx.x >> 4;
#pragma unroll
  for (int p = 0; p < 4; ++p) {
    float4 v = *(const float4*)&s[(size_t)(r0 + tr + p * 16) * C + c0 + tc];
    tile[tr + p * 16][tc + 0] = v.x;
    tile[tr + p * 16][tc + 1] = v.y;
    tile[tr + p * 16][tc + 2] = v.z;
    tile[tr + p * 16][tc + 3] = v.w;
  }
  __syncthreads();
  const int oc = threadIdx.x >> 4;
  const int orr = (threadIdx.x & 15) * 4;
#pragma unroll
  for (int p = 0; p < 4; ++p) {
    const int c = oc + p * 16;
    __hip_bfloat16 tmp[4];
    tmp[0] = __float2bfloat16(tile[orr + 0][c]);
    tmp[1] = __float2bfloat16(tile[orr + 1][c]);
    tmp[2] = __float2bfloat16(tile[orr + 2][c]);
    tmp[3] = __float2bfloat16(tile[orr + 3][c]);
    *(ushort4*)&d[(size_t)(c0 + c) * R + r0 + orr] = *(ushort4*)tmp;
  }
}

// ---------------- gating ----------------
__global__ __launch_bounds__(256) void gating_kernel(
    const float* __restrict__ x, const float* __restrict__ Wg, const float* __restrict__ bg,
    int* __restrict__ tok_e, float* __restrict__ tok_w,
    int* __restrict__ counts, float* __restrict__ importance) {
  const int tid = threadIdx.x, wid = tid >> 6, lane = tid & 63;
  const int t = blockIdx.x * 32 + wid * 8 + (lane >> 3);
  const int e = lane & 7;
  const float* xr = x + (size_t)t * DDIM;
  double dot = 0.0;
  for (int d = 0; d < DDIM; d += 4) {
    float4 xv = *(const float4*)(xr + d);
    dot += (double)xv.x * (double)Wg[(d + 0) * NEXP + e];
    dot += (double)xv.y * (double)Wg[(d + 1) * NEXP + e];
    dot += (double)xv.z * (double)Wg[(d + 2) * NEXP + e];
    dot += (double)xv.w * (double)Wg[(d + 3) * NEXP + e];
  }
  double logit = dot + (double)bg[e];
  double m = logit;
  for (int off = 1; off < 8; off <<= 1) {
    double o = __shfl_xor(m, off, 64);
    m = o > m ? o : m;
  }
  double p = exp(logit - m);
  double s = p;
  for (int off = 1; off < 8; off <<= 1) s += __shfl_xor(s, off, 64);
  float prob = (float)(p / s);

  __shared__ float imp[NEXP];
  __shared__ int cnt[NEXP];
  if (tid < NEXP) { imp[tid] = 0.f; cnt[tid] = 0; }
  __syncthreads();
  atomicAdd(&imp[e], prob);

  float bp = prob; int be = e;
  for (int off = 1; off < 8; off <<= 1) {
    float op = __shfl_xor(bp, off, 64); int oe = __shfl_xor(be, off, 64);
    if (op > bp || (op == bp && oe < be)) { bp = op; be = oe; }
  }
  float p2 = (e == be) ? -1.f : prob;
  float sp = p2; int se = e;
  for (int off = 1; off < 8; off <<= 1) {
    float op = __shfl_xor(sp, off, 64); int oe = __shfl_xor(se, off, 64);
    if (op > sp || (op == sp && oe < se)) { sp = op; se = oe; }
  }
  if (e == 0) {
    float tsum = bp + sp;
    tok_e[t * 2 + 0] = be; tok_e[t * 2 + 1] = se;
    tok_w[t * 2 + 0] = bp / tsum; tok_w[t * 2 + 1] = sp / tsum;
    atomicAdd(&cnt[be], 1); atomicAdd(&cnt[se], 1);
  }
  __syncthreads();
  if (tid < NEXP) {
    atomicAdd(&counts[tid], cnt[tid]);
    atomicAdd(&importance[tid], imp[tid]);
  }
}

// ---------------- routing (256-row tiles) ----------------
__global__ void offsets_kernel(const int* __restrict__ counts, int* pos, int* tile_expert,
                               int* meta, int* row_token) {
  if (threadIdx.x == 0) {
    int pb = 0, tb = 0;
    for (int e = 0; e < NEXP; e++) {
      pos[e] = pb;
      int tiles = (counts[e] + 255) >> 8;
      for (int tt = 0; tt < tiles; ++tt) tile_expert[tb + tt] = e;
      pb += tiles * 256; tb += tiles;
    }
    meta[0] = tb;
  }
  __syncthreads();
  for (int i = threadIdx.x; i < MAXROWS; i += blockDim.x) row_token[i] = -1;
}

__global__ void scatter_kernel(const int* __restrict__ tok_e, const float* __restrict__ tok_w,
                               int* __restrict__ pos, int* __restrict__ row_token,
                               float* __restrict__ row_weight, int* __restrict__ tok_row) {
  __shared__ int lcnt[NEXP], lbase[NEXP];
  const int t = blockIdx.x * 256 + threadIdx.x;
  if (threadIdx.x < NEXP) lcnt[threadIdx.x] = 0;
  __syncthreads();
  const int e0 = tok_e[t * 2 + 0], e1 = tok_e[t * 2 + 1];
  const int s0 = atomicAdd(&lcnt[e0], 1);
  const int s1 = atomicAdd(&lcnt[e1], 1);
  __syncthreads();
  if (threadIdx.x < NEXP) lbase[threadIdx.x] = atomicAdd(&pos[threadIdx.x], lcnt[threadIdx.x]);
  __syncthreads();
  int r0 = lbase[e0] + s0; row_token[r0] = t; row_weight[r0] = tok_w[t * 2 + 0]; tok_row[t * 2 + 0] = r0;
  int r1 = lbase[e1] + s1; row_token[r1] = t; row_weight[r1] = tok_w[t * 2 + 1]; tok_row[t * 2 + 1] = r1;
}

// ---------------- unified GEMM: C = [relu](A @ B^T + bias) ----------------
// 256x128 tile, BK=32, 4 waves, R0's exact 2-buffer __syncthreads schedule + swizzle.
// Rationale (R0..R8 ablations): MfmaUtil is pinned ~23% by staged-bytes throughput at the
// L2/L3 tier (~30 B/cyc/CU measured), NOT latency (R8 null), NOT conflicts (R5 null),
// NOT HBM (R7: FETCH halved, no gain). Fix = raise arithmetic intensity:
// BM*BN/(BM+BN): 64 -> 85 (staged bytes/FLOP x0.75), ds_read/MFMA 0.5 -> 0.375.
// Per wave: rows [wid*64,+64) x all 128 cols, acc[4][8] (~200 VGPR, capped 256 -> still
// 2 blocks/CU; LDS 48KB). Each wave stages its own 4 A-chunks + 2 B-chunks (16B/lane).
template<int NDIM, int KDIM, int NCOLT, bool GATHER, bool RELU>
__global__ __launch_bounds__(256, 2) void moe_gemm_kernel(
    const __hip_bfloat16* __restrict__ Ag, const __hip_bfloat16* __restrict__ Bg,
    const float* __restrict__ bias, __hip_bfloat16* __restrict__ Cg,
    const int* __restrict__ row_token, const int* __restrict__ tile_expert,
    const int* __restrict__ meta) {
  const int ty = blockIdx.x / NCOLT;      // tile-major: col-blocks of a row-tile consecutive
  const int cx = blockIdx.x % NCOLT;
  if (ty >= meta[0]) return;
  const int e = tile_expert[ty];
  const int r0 = ty * 256;
  const int n0 = cx * 128;
  const int tid = threadIdx.x, wid = tid >> 6, lane = tid & 63;

  __shared__ __align__(16) __hip_bfloat16 As[2][256 * 32];
  __shared__ __align__(16) __hip_bfloat16 Bs[2][128 * 32];

  // staging: chunk = 16 rows x 64B; lane -> row rl=lane>>2, slot lane&3 (linear 16B/lane)
  // global group inverse-swizzled: g = (slot ^ (srow&3))*8, srow&3 == rl&3
  const int rl = lane >> 2;
  const int g = ((lane & 3) ^ (rl & 3)) * 8;
  const __hip_bfloat16* gA[4];
  const __hip_bfloat16* gB[2];
#pragma unroll
  for (int m = 0; m < 4; ++m) {
    const int row = wid * 64 + m * 16 + rl;
    if (GATHER) {
      int t = row_token[r0 + row]; if (t < 0) t = 0;
      gA[m] = Ag + (size_t)t * KDIM + g;
    } else {
      gA[m] = Ag + (size_t)(r0 + row) * KDIM + g;
    }
  }
#pragma unroll
  for (int m = 0; m < 2; ++m)
    gB[m] = Bg + ((size_t)e * NDIM + n0 + wid * 32 + m * 16 + rl) * KDIM + g;
  const int ldsA = wid * 4 * 512;   // wave's first A chunk (elems)
  const int ldsB = wid * 2 * 512;

  f32x4 acc[4][8] = {};
  const int fr = lane & 15;
  const int soff = ((lane >> 4) ^ (lane & 3)) * 8;

#define STAGE(b) do { \
    async16(gA[0], &As[b][ldsA]);        async16(gA[1], &As[b][ldsA + 512]); \
    async16(gA[2], &As[b][ldsA + 1024]); async16(gA[3], &As[b][ldsA + 1536]); \
    async16(gB[0], &Bs[b][ldsB]);        async16(gB[1], &Bs[b][ldsB + 512]); \
    gA[0] += 32; gA[1] += 32; gA[2] += 32; gA[3] += 32; gB[0] += 32; gB[1] += 32; } while (0)

  STAGE(0);
  const int NT = KDIM / 32;
  for (int kt = 0; kt < NT; ++kt) {
    const int cur = kt & 1;
    __syncthreads();              // R0-proven drain schedule
    if (kt + 1 < NT) { if (cur) STAGE(0); else STAGE(1); }
    bf16x8 av[4], bv[8];
#pragma unroll
    for (int i = 0; i < 4; i++)
      av[i] = *(const bf16x8*)&As[cur][(wid * 64 + i * 16 + fr) * 32 + soff];
#pragma unroll
    for (int j = 0; j < 8; j++)
      bv[j] = *(const bf16x8*)&Bs[cur][(j * 16 + fr) * 32 + soff];
#pragma unroll
    for (int i = 0; i < 4; i++)
#pragma unroll
      for (int j = 0; j < 8; j++)
        acc[i][j] = __builtin_amdgcn_mfma_f32_16x16x32_bf16(av[i], bv[j], acc[i][j], 0, 0, 0);
  }
#undef STAGE

  const int crow = (lane >> 4) * 4;
  const int ccol = lane & 15;
#pragma unroll
  for (int j = 0; j < 8; j++) {
    const int gc = n0 + j * 16 + ccol;
    const float bb = bias[e * NDIM + gc];
#pragma unroll
    for (int i = 0; i < 4; i++) {
      const int gr = r0 + wid * 64 + i * 16 + crow;
#pragma unroll
      for (int r = 0; r < 4; r++) {
        float v = acc[i][j][r] + bb;
        if (RELU) v = v > 0.f ? v : 0.f;
        Cg[(size_t)(gr + r) * NDIM + gc] = __float2bfloat16(v);
      }
    }
  }
}

// ---------------- combine: out[t] = w0*row0 + w1*row1 ----------------
__global__ __launch_bounds__(256) void combine_kernel(
    const __hip_bfloat16* __restrict__ rowout, const int* __restrict__ tok_row,
    const float* __restrict__ row_weight, float* __restrict__ out) {
  const int idx = blockIdx.x * 256 + threadIdx.x;
  const int t = idx >> 7;
  const int d = (idx & 127) * 8;
  const int r0 = tok_row[t * 2 + 0], r1 = tok_row[t * 2 + 1];
  const float w0 = row_weight[r0], w1 = row_weight[r1];
  bf16x8 a = *(const bf16x8*)&rowout[(size_t)r0 * DDIM + d];
  bf16x8 b = *(const bf16x8*)&rowout[(size_t)r1 * DDIM + d];
  float o[8];
#pragma unroll
  for (int k = 0; k < 8; k++) o[k] = w0 * (float)a[k] + w1 * (float)b[k];
  float* dst = out + (size_t)t * DDIM + d;
  *(float4*)(dst + 0) = make_float4(o[0], o[1], o[2], o[3]);
  *(float4*)(dst + 4) = make_float4(o[4], o[5], o[6], o[7]);
}

// ---------------- lb_loss ----------------
__global__ void finalize_kernel(const float* __restrict__ importance,
                                const int* __restrict__ counts, float* __restrict__ lb_out) {
  if (threadIdx.x == 0 && blockIdx.x == 0) {
    float s = 0.f;
    for (int e = 0; e < NEXP; e++) s += importance[e];
    float lb = 0.f;
    for (int e = 0; e < NEXP; e++)
      lb += (importance[e] / s) * ((float)counts[e] / (float)(NTOK * KTOP));
    lb_out[0] = (float)NEXP * lb;
  }
}

// ---------------- launch ----------------
extern "C" void kernel_launch(void* const* d_in, const int* in_sizes, int n_in,
                              void* d_out, int out_size, void* d_ws, size_t ws_size,
                              hipStream_t stream) {
  (void)in_sizes; (void)n_in; (void)out_size; (void)ws_size;
  const float* x  = (const float*)d_in[0];
  const float* Wg = (const float*)d_in[1];
  const float* bg = (const float*)d_in[2];
  const float* W1 = (const float*)d_in[3];
  const float* b1 = (const float*)d_in[4];
  const float* W2 = (const float*)d_in[5];
  const float* b2 = (const float*)d_in[6];
  float* out = (float*)d_out;

  char* ws = (char*)d_ws;
  __hip_bfloat16* xb     = (__hip_bfloat16*)(ws + XB_OFF);
  __hip_bfloat16* w1t    = (__hip_bfloat16*)(ws + W1T_OFF);
  __hip_bfloat16* rowout = (__hip_bfloat16*)(ws + ROWOUT_OFF);
  __hip_bfloat16* w2t    = (__hip_bfloat16*)(ws + W2T_OFF);
  __hip_bfloat16* hb     = (__hip_bfloat16*)(ws + HB_OFF);
  int*   row_token  = (int*)(ws + ROWTOK_OFF);
  float* row_weight = (float*)(ws + ROWW_OFF);
  int*   tok_e   = (int*)(ws + TOKE_OFF);
  float* tok_w   = (float*)(ws + TOKW_OFF);
  int*   tok_row = (int*)(ws + TOKROW_OFF);
  int*   tile_e  = (int*)(ws + TILEE_OFF);
  int*   counts  = (int*)(ws + CNT_OFF);
  int*   pos     = (int*)(ws + POS_OFF);
  float* importance = (float*)(ws + IMP_OFF);
  int*   meta    = (int*)(ws + META_OFF);

  init_kernel<<<1, 64, 0, stream>>>(counts, importance);
  cast_x_kernel<<<NTOK * DDIM / 4 / 256, 256, 0, stream>>>(x, xb);
  transpose_cast_kernel<<<dim3(HDIM / 64, DDIM / 64, NEXP), 256, 0, stream>>>(W1, w1t, DDIM, HDIM);
  transpose_cast_kernel<<<dim3(DDIM / 64, HDIM / 64, NEXP), 256, 0, stream>>>(W2, w2t, HDIM, DDIM);
  gating_kernel<<<NTOK / 32, 256, 0, stream>>>(x, Wg, bg, tok_e, tok_w, counts, importance);
  offsets_kernel<<<1, 256, 0, stream>>>(counts, pos, tile_e, meta, row_token);
  scatter_kernel<<<NTOK / 256, 256, 0, stream>>>(tok_e, tok_w, pos, row_token, row_weight, tok_row);
  // gemm1: h = relu(x @ W1[e] + b1[e])   [gather A, N=4096, K=1024] : 72*32 = 2304 blocks
  moe_gemm_kernel<HDIM, DDIM, HDIM / 128, true, true>
      <<<MAXTILES * (HDIM / 128), 256, 0, stream>>>(xb, w1t, b1, hb, row_token, tile_e, meta);
  // gemm2: rowout = h @ W2[e] + b2[e]    [direct A, N=1024, K=4096] : 72*8 = 576 blocks
  moe_gemm_kernel<DDIM, HDIM, DDIM / 128, false, false>
      <<<MAXTILES * (DDIM / 128), 256, 0, stream>>>(hb, w2t, b2, rowout, row_token, tile_e, meta);
  combine_kernel<<<NTOK * 128 / 256, 256, 0, stream>>>(rowout, tok_row, row_weight, out);
  finalize_kernel<<<1, 64, 0, stream>>>(importance, counts, out + (size_t)NTOK * DDIM);
}

// Round 10
// 791.679 us; speedup vs baseline: 1.1961x; 1.1961x over previous
//
#include <hip/hip_runtime.h>
#include <hip/hip_bf16.h>
#include <math.h>

#define NTOK 8192
#define DDIM 1024
#define HDIM 4096
#define NEXP 8
#define KTOP 2
#define MAXROWS 17408   /* 16384 + 8*128 */
#define MAXTILES 136

typedef __bf16 bf16x8 __attribute__((ext_vector_type(8)));
typedef float f32x4 __attribute__((ext_vector_type(4)));

#define GAS __attribute__((address_space(1)))
#define LAS __attribute__((address_space(3)))

__device__ __forceinline__ void async16(const void* g, void* l) {
  __builtin_amdgcn_global_load_lds((GAS void*)g, (LAS void*)l, 16, 0, 0);
}

// ---------------- workspace layout (bytes) ----------------
#define XB_OFF     ((size_t)0)
#define W1T_OFF    (XB_OFF + (size_t)NTOK*DDIM*2)
#define ROWOUT_OFF W1T_OFF              /* w1t dead after gemm1; rowout 35.7MB < 64MB */
#define W2T_OFF    (W1T_OFF + (size_t)NEXP*DDIM*HDIM*2)
#define HB_OFF     (W2T_OFF + (size_t)NEXP*HDIM*DDIM*2)
#define ROWTOK_OFF (HB_OFF + (size_t)MAXROWS*HDIM*2)
#define ROWW_OFF   (ROWTOK_OFF + (size_t)MAXROWS*4)
#define TOKE_OFF   (ROWW_OFF + (size_t)MAXROWS*4)
#define TOKW_OFF   (TOKE_OFF + (size_t)NTOK*KTOP*4)
#define TOKROW_OFF (TOKW_OFF + (size_t)NTOK*KTOP*4)
#define TILEE_OFF  (TOKROW_OFF + (size_t)NTOK*KTOP*4)
#define CNT_OFF    (TILEE_OFF + (size_t)256*4)
#define POS_OFF    (CNT_OFF + 64)
#define IMP_OFF    (POS_OFF + 64)
#define META_OFF   (IMP_OFF + 64)

// ---------------- small utility kernels ----------------
__global__ void init_kernel(int* counts, float* importance) {
  if (threadIdx.x < NEXP) { counts[threadIdx.x] = 0; importance[threadIdx.x] = 0.f; }
}

__global__ void cast_x_kernel(const float* __restrict__ src, __hip_bfloat16* __restrict__ dst) {
  size_t i = ((size_t)blockIdx.x * blockDim.x + threadIdx.x) * 4;
  if (i < (size_t)NTOK * DDIM) {
    float4 v = *(const float4*)(src + i);
    dst[i + 0] = __float2bfloat16(v.x);
    dst[i + 1] = __float2bfloat16(v.y);
    dst[i + 2] = __float2bfloat16(v.z);
    dst[i + 3] = __float2bfloat16(v.w);
  }
}

// per-expert transpose+cast: src [E][R][C] fp32 -> dst [E][C][R] bf16
__global__ __launch_bounds__(256) void transpose_cast_kernel(
    const float* __restrict__ src, __hip_bfloat16* __restrict__ dst, int R, int C) {
  __shared__ float tile[64][65];
  const int e = blockIdx.z;
  const float* s = src + (size_t)e * R * C;
  __hip_bfloat16* d = dst + (size_t)e * R * C;
  const int c0 = blockIdx.x * 64, r0 = blockIdx.y * 64;
  const int tc = (threadIdx.x & 15) * 4;
  const int tr = threadIdx.x >> 4;
#pragma unroll
  for (int p = 0; p < 4; ++p) {
    float4 v = *(const float4*)&s[(size_t)(r0 + tr + p * 16) * C + c0 + tc];
    tile[tr + p * 16][tc + 0] = v.x;
    tile[tr + p * 16][tc + 1] = v.y;
    tile[tr + p * 16][tc + 2] = v.z;
    tile[tr + p * 16][tc + 3] = v.w;
  }
  __syncthreads();
  const int oc = threadIdx.x >> 4;
  const int orr = (threadIdx.x & 15) * 4;
#pragma unroll
  for (int p = 0; p < 4; ++p) {
    const int c = oc + p * 16;
    __hip_bfloat16 tmp[4];
    tmp[0] = __float2bfloat16(tile[orr + 0][c]);
    tmp[1] = __float2bfloat16(tile[orr + 1][c]);
    tmp[2] = __float2bfloat16(tile[orr + 2][c]);
    tmp[3] = __float2bfloat16(tile[orr + 3][c]);
    *(ushort4*)&d[(size_t)(c0 + c) * R + r0 + orr] = *(ushort4*)tmp;
  }
}

// ---------------- gating ----------------
__global__ __launch_bounds__(256) void gating_kernel(
    const float* __restrict__ x, const float* __restrict__ Wg, const float* __restrict__ bg,
    int* __restrict__ tok_e, float* __restrict__ tok_w,
    int* __restrict__ counts, float* __restrict__ importance) {
  const int tid = threadIdx.x, wid = tid >> 6, lane = tid & 63;
  const int t = blockIdx.x * 32 + wid * 8 + (lane >> 3);
  const int e = lane & 7;
  const float* xr = x + (size_t)t * DDIM;
  double dot = 0.0;
  for (int d = 0; d < DDIM; d += 4) {
    float4 xv = *(const float4*)(xr + d);
    dot += (double)xv.x * (double)Wg[(d + 0) * NEXP + e];
    dot += (double)xv.y * (double)Wg[(d + 1) * NEXP + e];
    dot += (double)xv.z * (double)Wg[(d + 2) * NEXP + e];
    dot += (double)xv.w * (double)Wg[(d + 3) * NEXP + e];
  }
  double logit = dot + (double)bg[e];
  double m = logit;
  for (int off = 1; off < 8; off <<= 1) {
    double o = __shfl_xor(m, off, 64);
    m = o > m ? o : m;
  }
  double p = exp(logit - m);
  double s = p;
  for (int off = 1; off < 8; off <<= 1) s += __shfl_xor(s, off, 64);
  float prob = (float)(p / s);

  __shared__ float imp[NEXP];
  __shared__ int cnt[NEXP];
  if (tid < NEXP) { imp[tid] = 0.f; cnt[tid] = 0; }
  __syncthreads();
  atomicAdd(&imp[e], prob);

  float bp = prob; int be = e;
  for (int off = 1; off < 8; off <<= 1) {
    float op = __shfl_xor(bp, off, 64); int oe = __shfl_xor(be, off, 64);
    if (op > bp || (op == bp && oe < be)) { bp = op; be = oe; }
  }
  float p2 = (e == be) ? -1.f : prob;
  float sp = p2; int se = e;
  for (int off = 1; off < 8; off <<= 1) {
    float op = __shfl_xor(sp, off, 64); int oe = __shfl_xor(se, off, 64);
    if (op > sp || (op == sp && oe < se)) { sp = op; se = oe; }
  }
  if (e == 0) {
    float tsum = bp + sp;
    tok_e[t * 2 + 0] = be; tok_e[t * 2 + 1] = se;
    tok_w[t * 2 + 0] = bp / tsum; tok_w[t * 2 + 1] = sp / tsum;
    atomicAdd(&cnt[be], 1); atomicAdd(&cnt[se], 1);
  }
  __syncthreads();
  if (tid < NEXP) {
    atomicAdd(&counts[tid], cnt[tid]);
    atomicAdd(&importance[tid], imp[tid]);
  }
}

// ---------------- routing ----------------
__global__ void offsets_kernel(const int* __restrict__ counts, int* pos, int* tile_expert,
                               int* meta, int* row_token) {
  if (threadIdx.x == 0) {
    int pb = 0, tb = 0;
    for (int e = 0; e < NEXP; e++) {
      pos[e] = pb;
      int tiles = (counts[e] + 127) >> 7;
      for (int tt = 0; tt < tiles; ++tt) tile_expert[tb + tt] = e;
      pb += tiles * 128; tb += tiles;
    }
    meta[0] = tb;
  }
  __syncthreads();
  for (int i = threadIdx.x; i < MAXROWS; i += blockDim.x) row_token[i] = -1;
}

__global__ void scatter_kernel(const int* __restrict__ tok_e, const float* __restrict__ tok_w,
                               int* __restrict__ pos, int* __restrict__ row_token,
                               float* __restrict__ row_weight, int* __restrict__ tok_row) {
  __shared__ int lcnt[NEXP], lbase[NEXP];
  const int t = blockIdx.x * 256 + threadIdx.x;
  if (threadIdx.x < NEXP) lcnt[threadIdx.x] = 0;
  __syncthreads();
  const int e0 = tok_e[t * 2 + 0], e1 = tok_e[t * 2 + 1];
  const int s0 = atomicAdd(&lcnt[e0], 1);
  const int s1 = atomicAdd(&lcnt[e1], 1);
  __syncthreads();
  if (threadIdx.x < NEXP) lbase[threadIdx.x] = atomicAdd(&pos[threadIdx.x], lcnt[threadIdx.x]);
  __syncthreads();
  int r0 = lbase[e0] + s0; row_token[r0] = t; row_weight[r0] = tok_w[t * 2 + 0]; tok_row[t * 2 + 0] = r0;
  int r1 = lbase[e1] + s1; row_token[r1] = t; row_weight[r1] = tok_w[t * 2 + 1]; tok_row[t * 2 + 1] = r1;
}

// ---------------- GEMM1: h = relu(x @ W1[e] + b1[e]), BK=32, double-buffered ----------------
// R6 structure (800us best). One change: __launch_bounds__(256,4) caps unified regs at
// 128/wave (64 acc-AGPR + <=64 VGPR) -> 4 blocks/CU instead of 2-3. Occupancy was the
// remaining limiter: staging supply (~14 B/cyc/CU) scales with resident waves (R7 proved
// it is NOT chip-BW-bound; R9 proved big tiles blow the L2 window: 128x128 is the optimum).
__global__ __launch_bounds__(256, 4) void gemm1_kernel(
    const __hip_bfloat16* __restrict__ xb, const __hip_bfloat16* __restrict__ w1t,
    const float* __restrict__ b1, __hip_bfloat16* __restrict__ hb,
    const int* __restrict__ row_token, const int* __restrict__ tile_expert,
    const int* __restrict__ meta) {
  const int tile_y = blockIdx.y;
  if (tile_y >= meta[0]) return;
  const int n0 = blockIdx.x * 128;
  const int e = tile_expert[tile_y];
  const int r0 = tile_y * 128;
  const int tid = threadIdx.x;
  const int wid = tid >> 6, lane = tid & 63;

  __shared__ __align__(16) __hip_bfloat16 As[2][128 * 32];
  __shared__ __align__(16) __hip_bfloat16 Bs[2][128 * 32];

  const int srow = wid * 32 + (lane >> 2);
  const int g = ((lane & 3) ^ (srow & 3)) * 8;   // swizzled 16B group (elements)
  int t0 = row_token[r0 + srow];      if (t0 < 0) t0 = 0;
  int t1 = row_token[r0 + srow + 16]; if (t1 < 0) t1 = 0;
  const __hip_bfloat16* ga0 = xb + (size_t)t0 * DDIM + g;
  const __hip_bfloat16* ga1 = xb + (size_t)t1 * DDIM + g;
  const __hip_bfloat16* gb0 = w1t + ((size_t)e * HDIM + n0 + srow) * DDIM + g;
  const __hip_bfloat16* gb1 = gb0 + (size_t)16 * DDIM;
  const int ldsA0 = (wid * 32) * 32, ldsA1 = (wid * 32 + 16) * 32;

  f32x4 acc[4][4] = {};
  const int wm = (wid & 1) * 64, wn = (wid >> 1) * 64;
  const int fr = lane & 15;
  const int soff = ((lane >> 4) ^ (lane & 3)) * 8;

#define STAGE1(b) do { \
    async16(ga0, &As[b][ldsA0]); async16(ga1, &As[b][ldsA1]); \
    async16(gb0, &Bs[b][ldsA0]); async16(gb1, &Bs[b][ldsA1]); \
    ga0 += 32; ga1 += 32; gb0 += 32; gb1 += 32; } while (0)

  STAGE1(0);
  for (int kt = 0; kt < DDIM / 32; ++kt) {
    const int cur = kt & 1;
    __syncthreads();              // vmcnt(0) drain: tile kt resident; prior reads done
    if (kt + 1 < DDIM / 32) { if (cur) STAGE1(0); else STAGE1(1); }
    bf16x8 av[4], bv[4];
#pragma unroll
    for (int i = 0; i < 4; i++) av[i] = *(const bf16x8*)&As[cur][(wm + i * 16 + fr) * 32 + soff];
#pragma unroll
    for (int j = 0; j < 4; j++) bv[j] = *(const bf16x8*)&Bs[cur][(wn + j * 16 + fr) * 32 + soff];
#pragma unroll
    for (int i = 0; i < 4; i++)
#pragma unroll
      for (int j = 0; j < 4; j++)
        acc[i][j] = __builtin_amdgcn_mfma_f32_16x16x32_bf16(av[i], bv[j], acc[i][j], 0, 0, 0);
  }
#undef STAGE1

  const int crow = (lane >> 4) * 4;
  const int ccol = lane & 15;
#pragma unroll
  for (int j = 0; j < 4; j++) {
    const int gc = n0 + wn + j * 16 + ccol;
    const float bias = b1[e * HDIM + gc];
#pragma unroll
    for (int i = 0; i < 4; i++) {
      const int grb = r0 + wm + i * 16 + crow;
#pragma unroll
      for (int r = 0; r < 4; r++) {
        float v = acc[i][j][r] + bias;
        v = v > 0.f ? v : 0.f;
        hb[(size_t)(grb + r) * HDIM + gc] = __float2bfloat16(v);
      }
    }
  }
}

// ---------------- GEMM2: rowout[r] = h[r] @ W2[e] + b2[e], BK=32, dbuf ----------------
// R6's tile-major mapping (id>>3) kept: 8 column-blocks of a row-tile are consecutive ids
// (co-timed hb panel sharing, R6's measured -20us). launch_bounds(256,4) for 4 blocks/CU:
// gemm2's 1088 blocks then fit ~one residency generation (tail was ~half the dispatch).
__global__ __launch_bounds__(256, 4) void gemm2_kernel(
    const __hip_bfloat16* __restrict__ hb, const __hip_bfloat16* __restrict__ w2t,
    const float* __restrict__ b2, __hip_bfloat16* __restrict__ rowout,
    const int* __restrict__ tile_expert, const int* __restrict__ meta) {
  const int tile_y = blockIdx.x >> 3;
  const int cx = blockIdx.x & 7;
  if (tile_y >= meta[0]) return;
  const int n0 = cx * 128;
  const int e = tile_expert[tile_y];
  const int r0 = tile_y * 128;
  const int tid = threadIdx.x;
  const int wid = tid >> 6, lane = tid & 63;

  __shared__ __align__(16) __hip_bfloat16 As[2][128 * 32];
  __shared__ __align__(16) __hip_bfloat16 Bs[2][128 * 32];

  const int srow = wid * 32 + (lane >> 2);
  const int g = ((lane & 3) ^ (srow & 3)) * 8;
  const __hip_bfloat16* ga0 = hb + ((size_t)r0 + srow) * HDIM + g;
  const __hip_bfloat16* ga1 = ga0 + (size_t)16 * HDIM;
  const __hip_bfloat16* gb0 = w2t + ((size_t)e * DDIM + n0 + srow) * HDIM + g;
  const __hip_bfloat16* gb1 = gb0 + (size_t)16 * HDIM;
  const int ldsA0 = (wid * 32) * 32, ldsA1 = (wid * 32 + 16) * 32;

  f32x4 acc[4][4] = {};
  const int wm = (wid & 1) * 64, wn = (wid >> 1) * 64;
  const int fr = lane & 15;
  const int soff = ((lane >> 4) ^ (lane & 3)) * 8;

#define STAGE2(b) do { \
    async16(ga0, &As[b][ldsA0]); async16(ga1, &As[b][ldsA1]); \
    async16(gb0, &Bs[b][ldsA0]); async16(gb1, &Bs[b][ldsA1]); \
    ga0 += 32; ga1 += 32; gb0 += 32; gb1 += 32; } while (0)

  STAGE2(0);
  for (int kt = 0; kt < HDIM / 32; ++kt) {
    const int cur = kt & 1;
    __syncthreads();
    if (kt + 1 < HDIM / 32) { if (cur) STAGE2(0); else STAGE2(1); }
    bf16x8 av[4], bv[4];
#pragma unroll
    for (int i = 0; i < 4; i++) av[i] = *(const bf16x8*)&As[cur][(wm + i * 16 + fr) * 32 + soff];
#pragma unroll
    for (int j = 0; j < 4; j++) bv[j] = *(const bf16x8*)&Bs[cur][(wn + j * 16 + fr) * 32 + soff];
#pragma unroll
    for (int i = 0; i < 4; i++)
#pragma unroll
      for (int j = 0; j < 4; j++)
        acc[i][j] = __builtin_amdgcn_mfma_f32_16x16x32_bf16(av[i], bv[j], acc[i][j], 0, 0, 0);
  }
#undef STAGE2

  const int crow = (lane >> 4) * 4;
  const int ccol = lane & 15;
#pragma unroll
  for (int j = 0; j < 4; j++) {
    const int gc = n0 + wn + j * 16 + ccol;
    const float bias = b2[e * DDIM + gc];
#pragma unroll
    for (int i = 0; i < 4; i++) {
      const int rr = r0 + wm + i * 16 + crow;
#pragma unroll
      for (int r = 0; r < 4; r++)
        rowout[(size_t)(rr + r) * DDIM + gc] = __float2bfloat16(acc[i][j][r] + bias);
    }
  }
}

// ---------------- combine: out[t] = w0*row0 + w1*row1 ----------------
__global__ __launch_bounds__(256) void combine_kernel(
    const __hip_bfloat16* __restrict__ rowout, const int* __restrict__ tok_row,
    const float* __restrict__ row_weight, float* __restrict__ out) {
  const int idx = blockIdx.x * 256 + threadIdx.x;
  const int t = idx >> 7;
  const int d = (idx & 127) * 8;
  const int r0 = tok_row[t * 2 + 0], r1 = tok_row[t * 2 + 1];
  const float w0 = row_weight[r0], w1 = row_weight[r1];
  bf16x8 a = *(const bf16x8*)&rowout[(size_t)r0 * DDIM + d];
  bf16x8 b = *(const bf16x8*)&rowout[(size_t)r1 * DDIM + d];
  float o[8];
#pragma unroll
  for (int k = 0; k < 8; k++) o[k] = w0 * (float)a[k] + w1 * (float)b[k];
  float* dst = out + (size_t)t * DDIM + d;
  *(float4*)(dst + 0) = make_float4(o[0], o[1], o[2], o[3]);
  *(float4*)(dst + 4) = make_float4(o[4], o[5], o[6], o[7]);
}

// ---------------- lb_loss ----------------
__global__ void finalize_kernel(const float* __restrict__ importance,
                                const int* __restrict__ counts, float* __restrict__ lb_out) {
  if (threadIdx.x == 0 && blockIdx.x == 0) {
    float s = 0.f;
    for (int e = 0; e < NEXP; e++) s += importance[e];
    float lb = 0.f;
    for (int e = 0; e < NEXP; e++)
      lb += (importance[e] / s) * ((float)counts[e] / (float)(NTOK * KTOP));
    lb_out[0] = (float)NEXP * lb;
  }
}

// ---------------- launch ----------------
extern "C" void kernel_launch(void* const* d_in, const int* in_sizes, int n_in,
                              void* d_out, int out_size, void* d_ws, size_t ws_size,
                              hipStream_t stream) {
  (void)in_sizes; (void)n_in; (void)out_size; (void)ws_size;
  const float* x  = (const float*)d_in[0];
  const float* Wg = (const float*)d_in[1];
  const float* bg = (const float*)d_in[2];
  const float* W1 = (const float*)d_in[3];
  const float* b1 = (const float*)d_in[4];
  const float* W2 = (const float*)d_in[5];
  const float* b2 = (const float*)d_in[6];
  float* out = (float*)d_out;

  char* ws = (char*)d_ws;
  __hip_bfloat16* xb     = (__hip_bfloat16*)(ws + XB_OFF);
  __hip_bfloat16* w1t    = (__hip_bfloat16*)(ws + W1T_OFF);
  __hip_bfloat16* rowout = (__hip_bfloat16*)(ws + ROWOUT_OFF);
  __hip_bfloat16* w2t    = (__hip_bfloat16*)(ws + W2T_OFF);
  __hip_bfloat16* hb     = (__hip_bfloat16*)(ws + HB_OFF);
  int*   row_token  = (int*)(ws + ROWTOK_OFF);
  float* row_weight = (float*)(ws + ROWW_OFF);
  int*   tok_e   = (int*)(ws + TOKE_OFF);
  float* tok_w   = (float*)(ws + TOKW_OFF);
  int*   tok_row = (int*)(ws + TOKROW_OFF);
  int*   tile_e  = (int*)(ws + TILEE_OFF);
  int*   counts  = (int*)(ws + CNT_OFF);
  int*   pos     = (int*)(ws + POS_OFF);
  float* importance = (float*)(ws + IMP_OFF);
  int*   meta    = (int*)(ws + META_OFF);

  init_kernel<<<1, 64, 0, stream>>>(counts, importance);
  cast_x_kernel<<<NTOK * DDIM / 4 / 256, 256, 0, stream>>>(x, xb);
  transpose_cast_kernel<<<dim3(HDIM / 64, DDIM / 64, NEXP), 256, 0, stream>>>(W1, w1t, DDIM, HDIM);
  transpose_cast_kernel<<<dim3(DDIM / 64, HDIM / 64, NEXP), 256, 0, stream>>>(W2, w2t, HDIM, DDIM);
  gating_kernel<<<NTOK / 32, 256, 0, stream>>>(x, Wg, bg, tok_e, tok_w, counts, importance);
  offsets_kernel<<<1, 256, 0, stream>>>(counts, pos, tile_e, meta, row_token);
  scatter_kernel<<<NTOK / 256, 256, 0, stream>>>(tok_e, tok_w, pos, row_token, row_weight, tok_row);
  gemm1_kernel<<<dim3(HDIM / 128, MAXTILES), 256, 0, stream>>>(xb, w1t, b1, hb, row_token, tile_e, meta);
  gemm2_kernel<<<dim3((DDIM / 128) * MAXTILES), 256, 0, stream>>>(hb, w2t, b2, rowout, tile_e, meta);
  combine_kernel<<<NTOK * 128 / 256, 256, 0, stream>>>(rowout, tok_row, row_weight, out);
  finalize_kernel<<<1, 64, 0, stream>>>(importance, counts, out + (size_t)NTOK * DDIM);
}